// Round 2
// baseline (140.504 us; speedup 1.0000x reference)
//
#include <hip/hip_runtime.h>

// Matcher v2 — n-split for write-BW.
// Origin-centered boxes: iw = min(aw,gtw), ih = min(ah,gth),
// iou = iw*ih / (aw*ah + gtw*gth - iw*ih).
// Outputs (float32, concat): matches [B,M] then ious [B,N,M].
//
// Kernel 1: grid = B*8 blocks (b, n-chunk of 128), 256 thr (4 waves).
//   Lane owns 4 adjacent m -> one global_store_dwordx4 covers a full
//   1 KB (b,n,:) row. 4 blocks/CU -> 16 waves/CU for store-queue overlap.
//   Per-block argmax partial (over its 128 n) -> ws.
// Kernel 2: reduce 8 chunk-partials per (b,m) -> matches.
// First-occurrence argmax: strict > with ascending n/wave/chunk order.

#define N_ANCH 1024
#define B_SZ   128
#define M_SZ   256
#define NSPLIT 8
#define NCHUNK (N_ANCH / NSPLIT)   // 128 n per block
#define NWAVES 4
#define NPW    (NCHUNK / NWAVES)   // 32 n per wave

__global__ __launch_bounds__(256) void iou_kernel(
    const float* __restrict__ anchors,   // [N,2]
    const float* __restrict__ gt,        // [B,M,4]
    float* __restrict__ ious,            // [B,N,M]
    float* __restrict__ ws_val,          // [B*NSPLIT, M]
    int*   __restrict__ ws_idx)          // [B*NSPLIT, M]
{
    __shared__ float2 s_anch[NCHUNK];          // 1 KB
    __shared__ float  s_val[NWAVES][M_SZ];     // 4 KB
    __shared__ int    s_idx[NWAVES][M_SZ];     // 4 KB

    const int tid   = threadIdx.x;
    const int lane  = tid & 63;
    const int w     = tid >> 6;
    const int b     = blockIdx.x / NSPLIT;
    const int chunk = blockIdx.x % NSPLIT;
    const int n0    = chunk * NCHUNK;

    if (tid < NCHUNK) s_anch[tid] = ((const float2*)anchors)[n0 + tid];

    // 4 gt boxes per lane (adjacent m).
    const int m0 = lane * 4;
    const float4* g4 = (const float4*)gt + b * M_SZ + m0;
    float gtw[4], gth[4], areab[4], bv[4];
    int   bi[4];
    #pragma unroll
    for (int j = 0; j < 4; ++j) {
        float4 g = g4[j];
        gtw[j] = g.z - g.x;
        gth[j] = g.w - g.y;
        areab[j] = gtw[j] * gth[j];
        bv[j] = -1.0f;
        bi[j] = 0;
    }
    __syncthreads();

    const int nw0 = n0 + w * NPW;
    float* __restrict__ row = ious + (size_t)(b * N_ANCH + nw0) * M_SZ + m0;

    #pragma unroll 4
    for (int i = 0; i < NPW; ++i) {
        float2 a = s_anch[w * NPW + i];      // wave-uniform -> broadcast
        float areaa = a.x * a.y;
        const int n = nw0 + i;
        float iou[4];
        #pragma unroll
        for (int j = 0; j < 4; ++j) {
            float iw = fminf(a.x, gtw[j]);
            float ih = fminf(a.y, gth[j]);
            float inter = iw * ih;
            iou[j] = __fdividef(inter, areaa + areab[j] - inter);
            if (iou[j] > bv[j]) { bv[j] = iou[j]; bi[j] = n; }
        }
        *(float4*)row = make_float4(iou[0], iou[1], iou[2], iou[3]);
        row += M_SZ;
    }

    #pragma unroll
    for (int j = 0; j < 4; ++j) {
        s_val[w][m0 + j] = bv[j];
        s_idx[w][m0 + j] = bi[j];
    }
    __syncthreads();

    // Combine 4 wave-partials per m (wave order = ascending n).
    {
        float v  = s_val[0][tid];
        int   ix = s_idx[0][tid];
        #pragma unroll
        for (int ww = 1; ww < NWAVES; ++ww) {
            float v2 = s_val[ww][tid];
            int   i2 = s_idx[ww][tid];
            if (v2 > v) { v = v2; ix = i2; }
        }
        ws_val[(b * NSPLIT + chunk) * M_SZ + tid] = v;
        ws_idx[(b * NSPLIT + chunk) * M_SZ + tid] = ix;
    }
}

__global__ __launch_bounds__(256) void argmax_kernel(
    const float* __restrict__ ws_val,
    const int*   __restrict__ ws_idx,
    float* __restrict__ matches)     // [B*M]
{
    const int t = blockIdx.x * 256 + threadIdx.x;   // t = b*M + m
    const int b = t >> 8;
    const int m = t & (M_SZ - 1);
    float v  = -1.0f;
    int   ix = 0;
    #pragma unroll
    for (int c = 0; c < NSPLIT; ++c) {              // ascending chunk = asc. n
        float v2 = ws_val[(b * NSPLIT + c) * M_SZ + m];
        int   i2 = ws_idx[(b * NSPLIT + c) * M_SZ + m];
        if (v2 > v) { v = v2; ix = i2; }
    }
    matches[t] = (float)ix;
}

extern "C" void kernel_launch(void* const* d_in, const int* in_sizes, int n_in,
                              void* d_out, int out_size, void* d_ws, size_t ws_size,
                              hipStream_t stream) {
    const float* anchors = (const float*)d_in[0];   // [1024,2]
    const float* gt      = (const float*)d_in[1];   // [128,256,4]
    float* out  = (float*)d_out;
    float* ious = out + (size_t)B_SZ * M_SZ;

    float* ws_val = (float*)d_ws;                              // 1 MB
    int*   ws_idx = (int*)d_ws + (size_t)B_SZ * NSPLIT * M_SZ; // 1 MB

    iou_kernel<<<dim3(B_SZ * NSPLIT), dim3(256), 0, stream>>>(
        anchors, gt, ious, ws_val, ws_idx);
    argmax_kernel<<<dim3(B_SZ * M_SZ / 256), dim3(256), 0, stream>>>(
        ws_val, ws_idx, out);
}